// Round 2
// baseline (878.542 us; speedup 1.0000x reference)
//
#include <hip/hip_runtime.h>

// BuildCost: light-field cost volume
//   x:    [1, 32, 81, 192, 192] fp32
//   mask: [1, 81, 192, 192]     fp32
//   W:    [128, 81]             fp32   (grouped 1x1, groups=32, m=4 per group)
//   out:  [1, 128, 9, 192, 192] fp32
//
// out[c*4+m, d+4, i, j] = (81/sum_t mask[t,i,j]) *
//     sum_{p,q} x[c, p*9+q, i+(4-p)*d, j+(4-q)*d] * mask[p*9+q, i, j] * W[c*4+m, p*9+q]
// with out-of-bounds x reads = 0 (zero padding).

#define AA   81
#define HH   192
#define WW   192
#define HW   (HH * WW)
#define NC   32
#define MM   4
#define ND   9

__global__ __launch_bounds__(256)
void buildcost_kernel(const float* __restrict__ x,
                      const float* __restrict__ mask,
                      const float* __restrict__ Wt,
                      float* __restrict__ out) {
    __shared__ float wlds[AA * MM];

    const int c  = blockIdx.z;
    const int tx = threadIdx.x & 15;
    const int ty = threadIdx.x >> 4;
    const int j  = blockIdx.x * 16 + tx;
    const int i  = blockIdx.y * 16 + ty;
    const int pix = i * WW + j;

    // Stage weights transposed: wlds[t*4+m] = W[(c*4+m)*81 + t]
    // NOTE: AA*MM = 324 > blockDim (256) -> strided loop, not a single if.
    for (int idx = threadIdx.x; idx < AA * MM; idx += 256) {
        const int t = idx >> 2;
        const int m = idx & 3;
        wlds[idx] = Wt[(c * MM + m) * AA + t];
    }
    __syncthreads();

    const float* __restrict__ xc = x + (size_t)c * AA * HW;

    float acc[ND][MM];
#pragma unroll
    for (int dd = 0; dd < ND; ++dd)
#pragma unroll
        for (int m = 0; m < MM; ++m) acc[dd][m] = 0.f;

    float msum = 0.f;

    int p = 0, q = 0;
#pragma unroll 1
    for (int t = 0; t < AA; ++t) {
        const float mval = mask[t * HW + pix];
        msum += mval;
        const float4 w4 = *(const float4*)&wlds[t * 4];
        const int kp = 4 - p;
        const int kq = 4 - q;
        const float* __restrict__ xt = xc + t * HW;

#pragma unroll
        for (int dd = 0; dd < ND; ++dd) {
            const int d  = dd - 4;
            const int y  = i + kp * d;
            const int xx = j + kq * d;
            float v = 0.f;
            if ((unsigned)y < (unsigned)HH && (unsigned)xx < (unsigned)WW)
                v = xt[y * WW + xx];
            const float s = v * mval;
            acc[dd][0] += s * w4.x;
            acc[dd][1] += s * w4.y;
            acc[dd][2] += s * w4.z;
            acc[dd][3] += s * w4.w;
        }

        if (++q == 9) { q = 0; ++p; }
    }

    const float inv = (float)AA / msum;

#pragma unroll
    for (int m = 0; m < MM; ++m)
#pragma unroll
        for (int dd = 0; dd < ND; ++dd)
            out[((size_t)(c * MM + m) * ND + dd) * HW + pix] = acc[dd][m] * inv;
}

extern "C" void kernel_launch(void* const* d_in, const int* in_sizes, int n_in,
                              void* d_out, int out_size, void* d_ws, size_t ws_size,
                              hipStream_t stream) {
    const float* x    = (const float*)d_in[0];
    const float* mask = (const float*)d_in[1];
    const float* Wt   = (const float*)d_in[2];
    float* out        = (float*)d_out;

    dim3 grid(WW / 16, HH / 16, NC);
    dim3 block(256);
    buildcost_kernel<<<grid, block, 0, stream>>>(x, mask, Wt, out);
}

// Round 3
// 876.657 us; speedup vs baseline: 1.0022x; 1.0022x over previous
//
#include <hip/hip_runtime.h>

// BuildCost: light-field cost volume
//   x:    [1, 32, 81, 192, 192] fp32
//   mask: [1, 81, 192, 192]     fp32
//   W:    [128, 81]             fp32   (grouped 1x1, groups=32, m=4 per group)
//   out:  [1, 128, 9, 192, 192] fp32
//
// out[c*4+m, d+4, i, j] = (81/sum_t mask[t,i,j]) *
//     sum_{p,q} x[c, p*9+q, i+(4-p)*d, j+(4-q)*d] * mask[p*9+q, i, j] * W[c*4+m, p*9+q]
// with out-of-bounds x reads = 0 (zero padding).

#define AA   81
#define HH   192
#define WW   192
#define HW   (HH * WW)
#define NC   32
#define MM   4
#define ND   9

// Grid: 4608 linear blocks. XCD-affinity swizzle: dispatch round-robins blocks
// over 8 XCDs (xcd = lin & 7), so put all 144 spatial tiles of a channel on ONE
// XCD: c = (lin&7) + 8*(slot/144). Each XCD then streams 4 channels' x-planes
// (taps swept in lockstep -> ~2-3 MB live set, fits 4 MiB per-XCD L2).

__global__ __launch_bounds__(256)
void buildcost_kernel(const float* __restrict__ x,
                      const float* __restrict__ mask,
                      const float* __restrict__ Wt,
                      float* __restrict__ out) {
    __shared__ float wlds[AA * MM];

    const int lin  = blockIdx.x;
    const int xcd  = lin & 7;
    const int slot = lin >> 3;          // [0, 576)
    const int cgrp = slot / 144;        // [0, 4)
    const int sp   = slot - cgrp * 144; // [0, 144)
    const int c    = xcd + (cgrp << 3);
    const int by   = sp / 12;
    const int bx   = sp - by * 12;

    const int tx = threadIdx.x & 15;
    const int ty = threadIdx.x >> 4;
    const int j  = bx * 16 + tx;
    const int i  = by * 16 + ty;
    const int pix = i * WW + j;

    // Stage weights transposed: wlds[t*4+m] = W[(c*4+m)*81 + t]  (324 > 256 -> loop)
    for (int idx = threadIdx.x; idx < AA * MM; idx += 256) {
        const int t = idx >> 2;
        const int m = idx & 3;
        wlds[idx] = Wt[(c * MM + m) * AA + t];
    }
    __syncthreads();

    const float* __restrict__ xc = x + (size_t)c * AA * HW;

    float acc[ND][MM];
#pragma unroll
    for (int dd = 0; dd < ND; ++dd)
#pragma unroll
        for (int m = 0; m < MM; ++m) acc[dd][m] = 0.f;

    float msum = 0.f;

    // Interior blocks (100/144): max shift is |kp*d| <= 16, so tiles with a
    // 16-px margin never leave the image -> no bounds predicates.
    const bool interior = (bx >= 1) & (bx <= 10) & (by >= 1) & (by <= 10);

    if (interior) {
        int p = 0, q = 0;
#pragma unroll 1
        for (int t = 0; t < AA; ++t) {
            const float mval = mask[t * HW + pix];
            msum += mval;
            const float4 w4 = *(const float4*)&wlds[t * 4];
            const int kp = 4 - p;
            const int kq = 4 - q;
            const int step = kp * WW + kq;                 // addr delta per +1 in d
            const float* __restrict__ base = xc + (size_t)t * HW + pix; // d = 0
#pragma unroll
            for (int dd = 0; dd < ND; ++dd) {
                const float v = base[(dd - 4) * step];
                const float s = v * mval;
                acc[dd][0] += s * w4.x;
                acc[dd][1] += s * w4.y;
                acc[dd][2] += s * w4.z;
                acc[dd][3] += s * w4.w;
            }
            if (++q == 9) { q = 0; ++p; }
        }
    } else {
        int p = 0, q = 0;
#pragma unroll 1
        for (int t = 0; t < AA; ++t) {
            const float mval = mask[t * HW + pix];
            msum += mval;
            const float4 w4 = *(const float4*)&wlds[t * 4];
            const int kp = 4 - p;
            const int kq = 4 - q;
            const float* __restrict__ xt = xc + (size_t)t * HW;
#pragma unroll
            for (int dd = 0; dd < ND; ++dd) {
                const int d  = dd - 4;
                const int y  = i + kp * d;
                const int xx = j + kq * d;
                float v = 0.f;
                if ((unsigned)y < (unsigned)HH && (unsigned)xx < (unsigned)WW)
                    v = xt[y * WW + xx];
                const float s = v * mval;
                acc[dd][0] += s * w4.x;
                acc[dd][1] += s * w4.y;
                acc[dd][2] += s * w4.z;
                acc[dd][3] += s * w4.w;
            }
            if (++q == 9) { q = 0; ++p; }
        }
    }

    const float inv = (float)AA / msum;

#pragma unroll
    for (int m = 0; m < MM; ++m)
#pragma unroll
        for (int dd = 0; dd < ND; ++dd)
            out[((size_t)(c * MM + m) * ND + dd) * HW + pix] = acc[dd][m] * inv;
}

extern "C" void kernel_launch(void* const* d_in, const int* in_sizes, int n_in,
                              void* d_out, int out_size, void* d_ws, size_t ws_size,
                              hipStream_t stream) {
    const float* x    = (const float*)d_in[0];
    const float* mask = (const float*)d_in[1];
    const float* Wt   = (const float*)d_in[2];
    float* out        = (float*)d_out;

    dim3 grid(12 * 12 * NC);
    dim3 block(256);
    buildcost_kernel<<<grid, block, 0, stream>>>(x, mask, Wt, out);
}